// Round 19
// baseline (438.948 us; speedup 1.0000x reference)
//
#include <hip/hip_runtime.h>

#define LOG2E 1.44269504088896340736f

typedef __attribute__((ext_vector_type(8))) _Float16 half8;
typedef __attribute__((ext_vector_type(4))) _Float16 half4;
typedef __attribute__((ext_vector_type(4))) float f32x4;
typedef __attribute__((ext_vector_type(2))) float f32x2;
typedef __attribute__((ext_vector_type(2))) unsigned int uint2v;

constexpr int CL       = 8;               // layers per staged chunk (divides 1000)
constexpr int LAYER_BY = 1536;            // bytes/layer: 64 lanes x (16B A0 + 8B A1)
constexpr int CHUNK_BY = CL * LAYER_BY;   // 12288
constexpr int CHUNK_V4 = CHUNK_BY / 16;   // 768 float4
constexpr int V4_PER_T = CHUNK_V4 / 64;   // 12 per thread (64-thread blocks)

// K=16 k-slot map (self-consistent between prepack/A and runtime/B):
//   chunk k0: slot(h,e) -> position 4h+e      (positions 0..15)
//   chunk k1: slot(h,e) -> position 16+4h+e   (16..19 real, 20 = bias, >20 pad)
// D layout (shape-determined, m89): col=lane&15, row=4*(lane>>4)+reg.

__device__ __forceinline__ unsigned short f16_rne(float f) {
    _Float16 h = (_Float16)f;   // RNE
    return __builtin_bit_cast(unsigned short, h);
}

// One block per layer; 64 threads (one per lane). Weights/bias PRE-SCALED by
// 0.5 (x = 0.5z feeds the Pade sigmoid directly), converted to f16.
__global__ void prepack(const float* __restrict__ W, const float* __restrict__ b,
                        unsigned int* __restrict__ wstream, int L)
{
    const int l    = blockIdx.x;
    const int lane = threadIdx.x;     // 0..63
    const int n    = lane & 15;       // tile0 neuron row
    const int h    = lane >> 4;

    unsigned short v[12];             // A0k0[4], A0k1[4], A1k1[4]
#pragma unroll
    for (int e = 0; e < 4; ++e) {
        v[e] = f16_rne(0.5f * W[(size_t)l * 400 + n * 20 + (4 * h + e)]);
        int p = 16 + 4 * h + e;
        float a = 0.f;
        if (p < 20)       a = 0.5f * W[(size_t)l * 400 + n * 20 + p];
        else if (p == 20) a = 0.5f * b[(size_t)l * 20 + n];
        v[4 + e] = f16_rne(a);
        float c = 0.f;
        int m1 = 16 + n;
        if (m1 < 20) {
            if (p < 20)       c = 0.5f * W[(size_t)l * 400 + m1 * 20 + p];
            else if (p == 20) c = 0.5f * b[(size_t)l * 20 + m1];
        }
        v[8 + e] = f16_rne(c);
    }
    unsigned w0 = (unsigned)v[0] | ((unsigned)v[1]  << 16);
    unsigned w1 = (unsigned)v[2] | ((unsigned)v[3]  << 16);
    unsigned w2 = (unsigned)v[4] | ((unsigned)v[5]  << 16);
    unsigned w3 = (unsigned)v[6] | ((unsigned)v[7]  << 16);
    unsigned w4 = (unsigned)v[8] | ((unsigned)v[9]  << 16);
    unsigned w5 = (unsigned)v[10]| ((unsigned)v[11] << 16);

    unsigned int* d0 = wstream + ((size_t)l * LAYER_BY + lane * 16) / 4;
    d0[0] = w0; d0[1] = w1; d0[2] = w2; d0[3] = w3;
    unsigned int* d1 = wstream + ((size_t)l * LAYER_BY + 1024 + lane * 8) / 4;
    d1[0] = w4; d1[1] = w5;
}

__device__ __forceinline__ unsigned pkrtz(float a, float b) {
    auto r = __builtin_amdgcn_cvt_pkrtz(a, b);   // __fp16 ext_vector(2)
    return __builtin_bit_cast(unsigned, r);
}
__device__ __forceinline__ half4 mk_half4(unsigned lo, unsigned hi) {
    uint2v u; u.x = lo; u.y = hi;
    return __builtin_bit_cast(half4, u);
}

__device__ __forceinline__ f32x2 make2(float v) { f32x2 r; r.x = v; r.y = v; return r; }

// sigmoid(z) with x = 0.5*z (scale folded into weights): 0.5 + x*N(u)/D(u).
// abs err <= ~2e-5 (|z|<=4), <= 1.2e-3 (z=8). Paired reciprocal: 1 rcp per 2
// divisions (rcp(dx*dy) * dy|dx) -> 4 rcp/layer instead of 8.
__device__ __forceinline__ f32x2 pade_sig(f32x2 x) {
    f32x2 u = x * x;
    f32x2 n = (u * make2(0.5f) + make2(52.5f)) * u + make2(472.5f);
    f32x2 d = (u * make2(15.0f) + make2(420.0f)) * u + make2(945.0f);
    float pr = __builtin_amdgcn_rcpf(d.x * d.y);
    f32x2 inv; inv.x = pr * d.y; inv.y = pr * d.x;
    return (x * n) * inv + make2(0.5f);
}

// full sigmoid for unscaled z (epilogue only, once)
__device__ __forceinline__ float sigm(float z) {
    return __builtin_amdgcn_rcpf(1.f + __builtin_amdgcn_exp2f(-LOG2E * z));
}

// Issue one layer's fragments: b128 (A0k0|A0k1) + b64 (A1k1). Volatile ->
// cannot be sunk. Immediate offsets walk the chunk's layers.
#define ISSUE_FRAG(base1, base2, OFF, A0, A1)                                   \
    asm volatile("ds_read_b128 %0, %1 offset:" #OFF : "=v"(A0) : "v"(base1));   \
    asm volatile("ds_read_b64 %0, %1 offset:" #OFF : "=v"(A1) : "v"(base2));

__device__ __forceinline__ void layer_step(const half8& a0, const half4& a1,
                                           half4& Bk0, half4& Bk1,
                                           f32x2 (&q)[4], int h) {
    const f32x4 z4 = {0.f, 0.f, 0.f, 0.f};
    const half4 A0k0 = __builtin_shufflevector(a0, a0, 0, 1, 2, 3);
    const half4 A0k1 = __builtin_shufflevector(a0, a0, 4, 5, 6, 7);
    // tile1 first: its D is on the loop-carried critical path (Bk1).
    f32x4 acc1 = __builtin_amdgcn_mfma_f32_16x16x16f16(a1,   Bk1, z4, 0, 0, 0);
    f32x4 acc0 = __builtin_amdgcn_mfma_f32_16x16x16f16(A0k0, Bk0, z4, 0, 0, 0);
    acc0       = __builtin_amdgcn_mfma_f32_16x16x16f16(A0k1, Bk1, acc0, 0, 0, 0);
    q[2].x = acc1[0]; q[2].y = acc1[1];
    q[3].x = acc1[2]; q[3].y = acc1[3];
    q[2] = pade_sig(q[2]); q[3] = pade_sig(q[3]);
    q[0].x = acc0[0]; q[0].y = acc0[1];
    q[1].x = acc0[2]; q[1].y = acc0[3];
    q[0] = pade_sig(q[0]); q[1] = pade_sig(q[1]);
    Bk0 = mk_half4(pkrtz(q[0].x, q[0].y), pkrtz(q[1].x, q[1].y));
    unsigned k1w0 = (h == 0) ? pkrtz(q[2].x, q[2].y)
                             : ((h == 1) ? 0x00003C00u : 0u);   // (1.0, 0) f16
    unsigned k1w1 = (h == 0) ? pkrtz(q[3].x, q[3].y) : 0u;
    Bk1 = mk_half4(k1w0, k1w1);
}

// 16 batch rows per wave; 1024 single-wave blocks (4/CU, 1 wave/SIMD).
// ZERO barriers: each wave stages its own chunk into its own private LDS
// double buffer. Same-wave DS ops are FIFO, so write->read of the same
// buffer needs no sync; waves drift into anti-phase, spreading LDS/trans/
// MFMA pipe demand instead of colliding at barrier-locked phases.
__global__ __launch_bounds__(64, 1) void mann_mfma(
    const float* __restrict__ x, const unsigned int* __restrict__ wstream,
    const float* __restrict__ Wout, const float* __restrict__ bout,
    float* __restrict__ out, int B, int L)
{
    __shared__ unsigned char lds[2 * CHUNK_BY];   // 24 KiB, private to this wave

    const int lane = threadIdx.x;     // 0..63
    const int c16  = lane & 15;
    const int h    = lane >> 4;
    const int w    = blockIdx.x;      // wave id 0..1023
    const int row  = w * 16 + c16;

    // ---- first-layer B fragments from x (unscaled; 0.5 lives in A) ----
    const float4 xa = *reinterpret_cast<const float4*>(x + (size_t)row * 20 + 4 * h);
    const float4 xb = *reinterpret_cast<const float4*>(x + (size_t)row * 20 + 16);
    half4 Bk0 = mk_half4(pkrtz(xa.x, xa.y), pkrtz(xa.z, xa.w));
    unsigned iw0 = (h == 0) ? pkrtz(xb.x, xb.y) : ((h == 1) ? 0x00003C00u : 0u);
    unsigned iw1 = (h == 0) ? pkrtz(xb.z, xb.w) : 0u;
    half4 Bk1 = mk_half4(iw0, iw1);

    // ---- private chunk staging: global->sreg early, sreg->LDS late ----
    float4 sreg[V4_PER_T];   // 12 float4 = 48 VGPRs in flight
    auto stage_load = [&](int c) {
        const float4* g = reinterpret_cast<const float4*>(wstream) + (size_t)c * CHUNK_V4;
#pragma unroll
        for (int j = 0; j < V4_PER_T; ++j) sreg[j] = g[j * 64 + lane];
    };
    auto stage_write = [&](int bufi) {
        float4* d = reinterpret_cast<float4*>(lds + bufi * CHUNK_BY);
#pragma unroll
        for (int j = 0; j < V4_PER_T; ++j) d[j * 64 + lane] = sreg[j];
    };

    const unsigned lbase = (unsigned)(uintptr_t)&lds[0];
    const unsigned b1A = lbase + lane * 16;          // b128 stream base
    const unsigned b2A = lbase + 1024 + lane * 8;    // b64 stream base
    const unsigned b1B = b1A + CHUNK_BY;
    const unsigned b2B = b2A + CHUNK_BY;

    stage_load(0);
    stage_write(0);          // compiler inserts vmcnt wait; no barrier needed

    // 4 named fragment buffers; buf[l & 3] holds layer l. Reads queue behind
    // the writes in this wave's DS FIFO -> data is correct without sync.
    half8 f0a, f1a, f2a, f3a;
    half4 f0b, f1b, f2b, f3b;

    ISSUE_FRAG(b1A, b2A, 0,    f0a, f0b);     // layer 0
    ISSUE_FRAG(b1A, b2A, 1536, f1a, f1b);     // layer 1

    f32x2 q[4];

    const int NC = L / CL;   // 125
    for (int c = 0; c < NC; ++c) {
        if (c + 1 < NC) stage_load(c + 1);            // global prefetch (vmcnt)
        const unsigned cb1 = (c & 1) ? b1B : b1A;
        const unsigned cb2 = (c & 1) ? b2B : b2A;
#pragma unroll
        for (int ll = 0; ll < CL; ++ll) {
            // 2 reads/layer; {ll, ll+1} outstanding -> drain oldest 2.
            if (ll == CL - 1) asm volatile("s_waitcnt lgkmcnt(0)");
            else              asm volatile("s_waitcnt lgkmcnt(2)");
            __builtin_amdgcn_sched_barrier(0);        // rule #18
            switch (ll + 2 < CL ? (ll + 2) : -1) {    // issue layer ll+2
                case 2: ISSUE_FRAG(cb1, cb2, 3072,  f2a, f2b); break;
                case 3: ISSUE_FRAG(cb1, cb2, 4608,  f3a, f3b); break;
                case 4: ISSUE_FRAG(cb1, cb2, 6144,  f0a, f0b); break;
                case 5: ISSUE_FRAG(cb1, cb2, 7680,  f1a, f1b); break;
                case 6: ISSUE_FRAG(cb1, cb2, 9216,  f2a, f2b); break;
                case 7: ISSUE_FRAG(cb1, cb2, 10752, f3a, f3b); break;
                default: break;
            }
            __builtin_amdgcn_sched_barrier(0);
            const int ci = ll & 3;
            if      (ci == 0) layer_step(f0a, f0b, Bk0, Bk1, q, h);
            else if (ci == 1) layer_step(f1a, f1b, Bk0, Bk1, q, h);
            else if (ci == 2) layer_step(f2a, f2b, Bk0, Bk1, q, h);
            else              layer_step(f3a, f3b, Bk0, Bk1, q, h);
        }
        if (c + 1 < NC) {
            __builtin_amdgcn_sched_barrier(0);        // pin writes after reads
            stage_write((c + 1) & 1);                 // vmcnt wait auto-inserted
            __builtin_amdgcn_sched_barrier(0);
            const unsigned nb1 = ((c + 1) & 1) ? b1B : b1A;
            const unsigned nb2 = ((c + 1) & 1) ? b2B : b2A;
            // These reads queue behind the writes above (same-wave DS FIFO).
            ISSUE_FRAG(nb1, nb2, 0,    f0a, f0b);     // next chunk layer 0
            ISSUE_FRAG(nb1, nb2, 1536, f1a, f1b);     // next chunk layer 1
        }
    }

    // ---- epilogue: lane (h,c16) holds neurons {4h+j} (q[0],q[1]) and
    // {16+4h+j} (q[2],q[3]; real only for h==0) ----
    const float4 woa = *reinterpret_cast<const float4*>(Wout + 4 * h);
    const float4 wob = *reinterpret_cast<const float4*>(Wout + 16);
    float part = q[0].x * woa.x + q[0].y * woa.y + q[1].x * woa.z + q[1].y * woa.w;
    const float m = (h == 0) ? 1.f : 0.f;
    part += m * (q[2].x * wob.x + q[2].y * wob.y + q[3].x * wob.z + q[3].y * wob.w);
    part += __shfl_xor(part, 16, 64);
    part += __shfl_xor(part, 32, 64);
    if (h == 0) out[row] = sigm(part + bout[0]);
}

extern "C" void kernel_launch(void* const* d_in, const int* in_sizes, int n_in,
                              void* d_out, int out_size, void* d_ws, size_t ws_size,
                              hipStream_t stream) {
    const float* x    = (const float*)d_in[0];
    const float* W    = (const float*)d_in[1];
    const float* b    = (const float*)d_in[2];
    const float* Wout = (const float*)d_in[3];
    const float* bout = (const float*)d_in[4];
    float* out = (float*)d_out;

    const int B = in_sizes[0] / 20;    // 16384
    const int L = in_sizes[1] / 400;   // 1000

    unsigned int* wstream = (unsigned int*)d_ws;   // L*1536 B = 1.54 MB

    prepack<<<L, 64, 0, stream>>>(W, b, wstream, L);

    const int grid = B / 16;           // 1024 single-wave blocks (4/CU)
    mann_mfma<<<grid, 64, 0, stream>>>(x, wstream, Wout, bout, out, B, L);
}

// Round 20
// 289.015 us; speedup vs baseline: 1.5188x; 1.5188x over previous
//
#include <hip/hip_runtime.h>

#define LOG2E 1.44269504088896340736f

typedef __attribute__((ext_vector_type(8))) _Float16 half8;
typedef __attribute__((ext_vector_type(4))) _Float16 half4;
typedef __attribute__((ext_vector_type(4))) float f32x4;
typedef __attribute__((ext_vector_type(2))) float f32x2;
typedef __attribute__((ext_vector_type(2))) unsigned int uint2v;

constexpr int CL       = 8;               // layers per staged chunk (divides 1000)
constexpr int LAYER_BY = 2048;            // bytes/layer: 64 lanes x (16B A0 + 16B A1)
constexpr int CHUNK_BY = CL * LAYER_BY;   // 16384
constexpr int CHUNK_V4 = CHUNK_BY / 16;   // 1024 float4
constexpr int V4_PER_T = CHUNK_V4 / 256;  // 4 per thread

// K=16 k-slot map (self-consistent between prepack/A and runtime/B):
//   k0 MFMA: slot(h,e) -> position 4h+e      (positions 0..15)
//   k1 MFMA: slot(h,e) -> position 16+4h+e   (16..19 real, 20 = bias, >20 pad)
// BOTH tiles get BOTH K-halves (r15 dropped A1k0 -> silently wrong neurons
// 16-19, passing only via fixed-point attenuation; fixed here).
// D layout (shape-determined, m89): col=lane&15, row=4*(lane>>4)+reg.

__device__ __forceinline__ unsigned short f16_rne(float f) {
    _Float16 h = (_Float16)f;   // RNE
    return __builtin_bit_cast(unsigned short, h);
}

// One block per layer; 64 threads (one per lane). Weights/bias PRE-SCALED by
// 0.5 (x = 0.5z feeds the Pade sigmoid directly), converted to f16.
__global__ void prepack(const float* __restrict__ W, const float* __restrict__ b,
                        unsigned int* __restrict__ wstream, int L)
{
    const int l    = blockIdx.x;
    const int lane = threadIdx.x;     // 0..63
    const int n    = lane & 15;       // tile0 neuron row
    const int h    = lane >> 4;
    const int m1   = 16 + n;          // tile1 neuron row (real for n<4)

    unsigned short v[16];             // A0k0[4], A0k1[4], A1k0[4], A1k1[4]
#pragma unroll
    for (int e = 0; e < 4; ++e) {
        const int p0 = 4 * h + e;         // k0 position
        const int p1 = 16 + 4 * h + e;    // k1 position
        // A0: neuron n (always < 20)
        v[e] = f16_rne(0.5f * W[(size_t)l * 400 + n * 20 + p0]);
        float a = 0.f;
        if (p1 < 20)       a = 0.5f * W[(size_t)l * 400 + n * 20 + p1];
        else if (p1 == 20) a = 0.5f * b[(size_t)l * 20 + n];
        v[4 + e] = f16_rne(a);
        // A1: neuron m1 (real only for m1 < 20)
        float c0 = 0.f, c1 = 0.f;
        if (m1 < 20) {
            c0 = 0.5f * W[(size_t)l * 400 + m1 * 20 + p0];
            if (p1 < 20)       c1 = 0.5f * W[(size_t)l * 400 + m1 * 20 + p1];
            else if (p1 == 20) c1 = 0.5f * b[(size_t)l * 20 + m1];
        }
        v[8 + e]  = f16_rne(c0);
        v[12 + e] = f16_rne(c1);
    }
    unsigned wd[8];
#pragma unroll
    for (int i = 0; i < 8; ++i)
        wd[i] = (unsigned)v[2*i] | ((unsigned)v[2*i+1] << 16);

    unsigned int* d0 = wstream + ((size_t)l * LAYER_BY + lane * 16) / 4;
    d0[0] = wd[0]; d0[1] = wd[1]; d0[2] = wd[2]; d0[3] = wd[3];
    unsigned int* d1 = wstream + ((size_t)l * LAYER_BY + 1024 + lane * 16) / 4;
    d1[0] = wd[4]; d1[1] = wd[5]; d1[2] = wd[6]; d1[3] = wd[7];
}

__device__ __forceinline__ unsigned pkrtz(float a, float b) {
    auto r = __builtin_amdgcn_cvt_pkrtz(a, b);   // __fp16 ext_vector(2)
    return __builtin_bit_cast(unsigned, r);
}
__device__ __forceinline__ half4 mk_half4(unsigned lo, unsigned hi) {
    uint2v u; u.x = lo; u.y = hi;
    return __builtin_bit_cast(half4, u);
}

__device__ __forceinline__ f32x2 make2(float v) { f32x2 r; r.x = v; r.y = v; return r; }

// sigmoid(z) with x = 0.5*z (scale folded into weights): 0.5 + x*N(u)/D(u).
// abs err <= ~2e-5 (|z|<=4), <= 1.2e-3 (z=8). Paired reciprocal: 1 rcp per 2
// divisions (rcp(dx*dy) * dy|dx) -> 4 rcp/layer instead of 8.
__device__ __forceinline__ f32x2 pade_sig(f32x2 x) {
    f32x2 u = x * x;
    f32x2 n = (u * make2(0.5f) + make2(52.5f)) * u + make2(472.5f);
    f32x2 d = (u * make2(15.0f) + make2(420.0f)) * u + make2(945.0f);
    float pr = __builtin_amdgcn_rcpf(d.x * d.y);
    f32x2 inv; inv.x = pr * d.y; inv.y = pr * d.x;
    return (x * n) * inv + make2(0.5f);
}

// full sigmoid for unscaled z (epilogue only, once)
__device__ __forceinline__ float sigm(float z) {
    return __builtin_amdgcn_rcpf(1.f + __builtin_amdgcn_exp2f(-LOG2E * z));
}

// Issue one layer's fragments: two b128 (A0 = k0|k1, A1 = k0|k1). Volatile ->
// cannot be sunk. Immediate offsets walk the chunk's layers.
#define ISSUE_FRAG(base1, base2, OFF, A0, A1)                                   \
    asm volatile("ds_read_b128 %0, %1 offset:" #OFF : "=v"(A0) : "v"(base1));   \
    asm volatile("ds_read_b128 %0, %1 offset:" #OFF : "=v"(A1) : "v"(base2));

__device__ __forceinline__ void layer_step(const half8& a0, const half8& a1,
                                           half4& Bk0, half4& Bk1,
                                           f32x2 (&q)[4], int h) {
    const f32x4 z4 = {0.f, 0.f, 0.f, 0.f};
    const half4 A0k0 = __builtin_shufflevector(a0, a0, 0, 1, 2, 3);
    const half4 A0k1 = __builtin_shufflevector(a0, a0, 4, 5, 6, 7);
    const half4 A1k0 = __builtin_shufflevector(a1, a1, 0, 1, 2, 3);
    const half4 A1k1 = __builtin_shufflevector(a1, a1, 4, 5, 6, 7);
    // Both tiles: full K via 2-MFMA C-chain (k0 then k1). Tile1 first: its D
    // feeds the loop-carried Bk1.
    f32x4 acc1 = __builtin_amdgcn_mfma_f32_16x16x16f16(A1k0, Bk0, z4, 0, 0, 0);
    f32x4 acc0 = __builtin_amdgcn_mfma_f32_16x16x16f16(A0k0, Bk0, z4, 0, 0, 0);
    acc1       = __builtin_amdgcn_mfma_f32_16x16x16f16(A1k1, Bk1, acc1, 0, 0, 0);
    acc0       = __builtin_amdgcn_mfma_f32_16x16x16f16(A0k1, Bk1, acc0, 0, 0, 0);
    q[2].x = acc1[0]; q[2].y = acc1[1];
    q[3].x = acc1[2]; q[3].y = acc1[3];
    q[2] = pade_sig(q[2]); q[3] = pade_sig(q[3]);
    q[0].x = acc0[0]; q[0].y = acc0[1];
    q[1].x = acc0[2]; q[1].y = acc0[3];
    q[0] = pade_sig(q[0]); q[1] = pade_sig(q[1]);
    Bk0 = mk_half4(pkrtz(q[0].x, q[0].y), pkrtz(q[1].x, q[1].y));
    unsigned k1w0 = (h == 0) ? pkrtz(q[2].x, q[2].y)
                             : ((h == 1) ? 0x00003C00u : 0u);   // (1.0, 0) f16
    unsigned k1w1 = (h == 0) ? pkrtz(q[3].x, q[3].y) : 0u;
    Bk1 = mk_half4(k1w0, k1w1);
}

// 16 batch rows per wave; 1024 waves = 1/SIMD (structural). r9-proven LDS
// skeleton; K=16 f16 MFMAs, 2 C-chained per tile (full K for both tiles).
__global__ __launch_bounds__(256, 1) void mann_mfma(
    const float* __restrict__ x, const unsigned int* __restrict__ wstream,
    const float* __restrict__ Wout, const float* __restrict__ bout,
    float* __restrict__ out, int B, int L)
{
    __shared__ unsigned char lds[2 * CHUNK_BY];   // 32 KiB double buffer

    const int tid  = threadIdx.x;
    const int lane = tid & 63;
    const int c16  = lane & 15;
    const int h    = lane >> 4;
    const int w    = (blockIdx.x * 256 + tid) >> 6;
    const int row  = w * 16 + c16;

    // ---- first-layer B fragments from x (unscaled; 0.5 lives in A) ----
    const float4 xa = *reinterpret_cast<const float4*>(x + (size_t)row * 20 + 4 * h);
    const float4 xb = *reinterpret_cast<const float4*>(x + (size_t)row * 20 + 16);
    half4 Bk0 = mk_half4(pkrtz(xa.x, xa.y), pkrtz(xa.z, xa.w));
    unsigned iw0 = (h == 0) ? pkrtz(xb.x, xb.y) : ((h == 1) ? 0x00003C00u : 0u);
    unsigned iw1 = (h == 0) ? pkrtz(xb.z, xb.w) : 0u;
    half4 Bk1 = mk_half4(iw0, iw1);

    // ---- chunk staging: global->reg early, reg->LDS late ----
    float4 sreg[V4_PER_T];
    auto stage_load = [&](int c) {
        const float4* g = reinterpret_cast<const float4*>(wstream) + (size_t)c * CHUNK_V4;
#pragma unroll
        for (int j = 0; j < V4_PER_T; ++j) sreg[j] = g[j * 256 + tid];
    };
    auto stage_write = [&](int bufi) {
        float4* d = reinterpret_cast<float4*>(lds + bufi * CHUNK_BY);
#pragma unroll
        for (int j = 0; j < V4_PER_T; ++j) d[j * 256 + tid] = sreg[j];
    };

    const unsigned lbase = (unsigned)(uintptr_t)&lds[0];
    const unsigned b1A = lbase + lane * 16;          // A0 stream base
    const unsigned b2A = lbase + 1024 + lane * 16;   // A1 stream base
    const unsigned b1B = b1A + CHUNK_BY;
    const unsigned b2B = b2A + CHUNK_BY;

    stage_load(0); stage_write(0); __syncthreads();

    // 4 named fragment buffers; buf[l & 3] holds layer l.
    half8 f0a, f1a, f2a, f3a;
    half8 f0b, f1b, f2b, f3b;

    ISSUE_FRAG(b1A, b2A, 0,    f0a, f0b);     // layer 0
    ISSUE_FRAG(b1A, b2A, 2048, f1a, f1b);     // layer 1

    f32x2 q[4];

    const int NC = L / CL;   // 125
    for (int c = 0; c < NC; ++c) {
        if (c + 1 < NC) stage_load(c + 1);            // global prefetch (vmcnt)
        const unsigned cb1 = (c & 1) ? b1B : b1A;
        const unsigned cb2 = (c & 1) ? b2B : b2A;
#pragma unroll
        for (int ll = 0; ll < CL; ++ll) {
            // 2 reads/layer; {ll, ll+1} outstanding -> drain oldest 2.
            if (ll == CL - 1) asm volatile("s_waitcnt lgkmcnt(0)");
            else              asm volatile("s_waitcnt lgkmcnt(2)");
            __builtin_amdgcn_sched_barrier(0);        // rule #18
            switch (ll + 2 < CL ? (ll + 2) : -1) {    // issue layer ll+2
                case 2: ISSUE_FRAG(cb1, cb2, 4096,  f2a, f2b); break;
                case 3: ISSUE_FRAG(cb1, cb2, 6144,  f3a, f3b); break;
                case 4: ISSUE_FRAG(cb1, cb2, 8192,  f0a, f0b); break;
                case 5: ISSUE_FRAG(cb1, cb2, 10240, f1a, f1b); break;
                case 6: ISSUE_FRAG(cb1, cb2, 12288, f2a, f2b); break;
                case 7: ISSUE_FRAG(cb1, cb2, 14336, f3a, f3b); break;
                default: break;
            }
            __builtin_amdgcn_sched_barrier(0);
            const int ci = ll & 3;
            if      (ci == 0) layer_step(f0a, f0b, Bk0, Bk1, q, h);
            else if (ci == 1) layer_step(f1a, f1b, Bk0, Bk1, q, h);
            else if (ci == 2) layer_step(f2a, f2b, Bk0, Bk1, q, h);
            else              layer_step(f3a, f3b, Bk0, Bk1, q, h);
        }
        if (c + 1 < NC) {
            stage_write((c + 1) & 1);                 // loads long since landed
            __syncthreads();
            const unsigned nb1 = ((c + 1) & 1) ? b1B : b1A;
            const unsigned nb2 = ((c + 1) & 1) ? b2B : b2A;
            ISSUE_FRAG(nb1, nb2, 0,    f0a, f0b);     // next chunk layer 0
            ISSUE_FRAG(nb1, nb2, 2048, f1a, f1b);     // next chunk layer 1
        }
    }

    // ---- epilogue: lane (h,c16) holds neurons {4h+j} (q[0],q[1]) and
    // {16+4h+j} (q[2],q[3]; real only for h==0) ----
    const float4 woa = *reinterpret_cast<const float4*>(Wout + 4 * h);
    const float4 wob = *reinterpret_cast<const float4*>(Wout + 16);
    float part = q[0].x * woa.x + q[0].y * woa.y + q[1].x * woa.z + q[1].y * woa.w;
    const float m = (h == 0) ? 1.f : 0.f;
    part += m * (q[2].x * wob.x + q[2].y * wob.y + q[3].x * wob.z + q[3].y * wob.w);
    part += __shfl_xor(part, 16, 64);
    part += __shfl_xor(part, 32, 64);
    if (h == 0) out[row] = sigm(part + bout[0]);
}

extern "C" void kernel_launch(void* const* d_in, const int* in_sizes, int n_in,
                              void* d_out, int out_size, void* d_ws, size_t ws_size,
                              hipStream_t stream) {
    const float* x    = (const float*)d_in[0];
    const float* W    = (const float*)d_in[1];
    const float* b    = (const float*)d_in[2];
    const float* Wout = (const float*)d_in[3];
    const float* bout = (const float*)d_in[4];
    float* out = (float*)d_out;

    const int B = in_sizes[0] / 20;    // 16384
    const int L = in_sizes[1] / 400;   // 1000

    unsigned int* wstream = (unsigned int*)d_ws;   // L*2048 B = 2.05 MB

    prepack<<<L, 64, 0, stream>>>(W, b, wstream, L);

    const int grid = B / 64;           // 16 rows/wave, 4 waves/block
    mann_mfma<<<grid, 256, 0, stream>>>(x, wstream, Wout, bout, out, B, L);
}

// Round 21
// 272.405 us; speedup vs baseline: 1.6114x; 1.0610x over previous
//
#include <hip/hip_runtime.h>

#define LOG2E 1.44269504088896340736f

typedef __attribute__((ext_vector_type(8))) short short8;
typedef __attribute__((ext_vector_type(4))) float f32x4;
typedef __attribute__((ext_vector_type(2))) float f32x2;

constexpr int CL       = 20;              // layers per staged chunk
constexpr int LAYER_BY = 2048;            // bytes/layer: 2 tiles x 64 lanes x 16B
constexpr int CHUNK_BY = CL * LAYER_BY;   // 40960
constexpr int CHUNK_V4 = CHUNK_BY / 16;   // 2560 float4
constexpr int V4_PER_T = CHUNK_V4 / 256;  // 10 per thread

// k-slot -> logical input position (same map in prepack/A and runtime/B, so
// the HW k-order cancels). pos 20 carries bias (B supplies 1.0); pos>20 pad=0.
__device__ __forceinline__ int slot_pos(int h, int e) {
    return (e < 4) ? (4 * h + e) : (16 + 4 * h + (e - 4));
}

__device__ __forceinline__ unsigned short f32_to_bf16_rne(float f) {
    unsigned u = __builtin_bit_cast(unsigned, f);
    unsigned r = 0x7fffu + ((u >> 16) & 1u);
    return (unsigned short)((u + r) >> 16);
}

// One block per layer; 128 threads = 2 tiles x 64 lanes. Weights/bias are
// PRE-SCALED by 0.5: acc = 0.5*z = x, feeding the Pade sigmoid directly.
__global__ void prepack(const float* __restrict__ W, const float* __restrict__ b,
                        unsigned int* __restrict__ wstream, int L)
{
    const int l    = blockIdx.x;
    const int t    = threadIdx.x >> 6;
    const int lane = threadIdx.x & 63;
    const int n    = t * 16 + (lane & 15);   // output-neuron position
    const int h    = lane >> 4;
    unsigned int words[4];
#pragma unroll
    for (int d = 0; d < 4; ++d) {
        unsigned short halves[2];
#pragma unroll
        for (int half = 0; half < 2; ++half) {
            int e   = d * 2 + half;
            int pos = slot_pos(h, e);
            float v = 0.f;
            if (n < 20) {
                if (pos < 20)       v = W[(size_t)l * 400 + n * 20 + pos];
                else if (pos == 20) v = b[(size_t)l * 20 + n];
            }
            halves[half] = f32_to_bf16_rne(v * 0.5f);
        }
        words[d] = (unsigned)halves[0] | ((unsigned)halves[1] << 16);
    }
    unsigned int* dst = wstream + ((size_t)l * LAYER_BY + t * 1024 + lane * 16) / 4;
    dst[0] = words[0]; dst[1] = words[1]; dst[2] = words[2]; dst[3] = words[3];
}

__device__ __forceinline__ unsigned cvt_pk_bf16(float lo, float hi) {
    unsigned r;
    asm("v_cvt_pk_bf16_f32 %0, %1, %2" : "=v"(r) : "v"(lo), "v"(hi));
    return r;
}

// Mask pad slots: h==0 keeps real positions 16..19; h==1 slot e=4 is pos 20
// -> constant 1.0 (bias multiplier); other upper-half slots hit zero A columns.
__device__ __forceinline__ short8 finalize_B(unsigned p0, unsigned p1,
                                             unsigned p2, unsigned p3, int h) {
    if (h != 0) { p2 = (h == 1) ? 0x00003F80u : 0u; p3 = 0u; }
    union { unsigned u[4]; short8 s; } cv;
    cv.u[0] = p0; cv.u[1] = p1; cv.u[2] = p2; cv.u[3] = p3;
    return cv.s;
}

__device__ __forceinline__ f32x2 make2(float v) { f32x2 r; r.x = v; r.y = v; return r; }

// sigmoid(z) with x = 0.5*z already in acc: sigma = 0.5 + x*Ntil(u)/D(u),
// u = x^2. abs err <= ~2e-5 for |z|<=4, <= 1.2e-3 at |z|=8. Packed f32 ops.
__device__ __forceinline__ f32x2 pade_sig(f32x2 x) {
    f32x2 u = x * x;
    f32x2 n = (u * make2(0.5f) + make2(52.5f)) * u + make2(472.5f);
    f32x2 d = (u * make2(15.0f) + make2(420.0f)) * u + make2(945.0f);
    f32x2 r;
    r.x = __builtin_amdgcn_rcpf(d.x);
    r.y = __builtin_amdgcn_rcpf(d.y);
    return (x * n) * r + make2(0.5f);
}

// full sigmoid for unscaled z (epilogue only, once)
__device__ __forceinline__ float sigm(float z) {
    return __builtin_amdgcn_rcpf(1.f + __builtin_amdgcn_exp2f(-LOG2E * z));
}

// Issue both A-fragment reads for one layer (volatile -> cannot be sunk).
__device__ __forceinline__ void issue_frag(unsigned addr, short8& t0, short8& t1) {
    asm volatile("ds_read_b128 %0, %1 offset:0"    : "=v"(t0) : "v"(addr));
    asm volatile("ds_read_b128 %0, %1 offset:1024" : "=v"(t1) : "v"(addr));
}

__device__ __forceinline__ void layer_step(const short8& c0, const short8& c1,
                                           short8& Bf, f32x2& q0, f32x2& q1,
                                           f32x2& q2, f32x2& q3, int h) {
    const f32x4 zero = {0.f, 0.f, 0.f, 0.f};
    f32x4 acc0 = __builtin_amdgcn_mfma_f32_16x16x32_bf16(c0, Bf, zero, 0, 0, 0);
    f32x4 acc1 = __builtin_amdgcn_mfma_f32_16x16x32_bf16(c1, Bf, zero, 0, 0, 0);
    q0.x = acc0[0]; q0.y = acc0[1];
    q1.x = acc0[2]; q1.y = acc0[3];
    q2.x = acc1[0]; q2.y = acc1[1];
    q3.x = acc1[2]; q3.y = acc1[3];
    q0 = pade_sig(q0); q1 = pade_sig(q1);
    q2 = pade_sig(q2); q3 = pade_sig(q3);
    Bf = finalize_B(cvt_pk_bf16(q0.x, q0.y), cvt_pk_bf16(q1.x, q1.y),
                    cvt_pk_bf16(q2.x, q2.y), cvt_pk_bf16(q3.x, q3.y), h);
}

// 16 batch rows per wave via 16x16x32 MFMA; 1024 waves = 1/SIMD (structural).
// A-fragments prefetched 2 LAYERS ahead (4 named buffers, counted lgkmcnt(2)
// waits) so the ds_read latency is fully covered by ~2 layers of compute.
__global__ __launch_bounds__(256, 1) void mann_mfma(
    const float* __restrict__ x, const unsigned int* __restrict__ wstream,
    const float* __restrict__ Wout, const float* __restrict__ bout,
    float* __restrict__ out, int B, int L)
{
    __shared__ unsigned char lds[2 * CHUNK_BY];   // 80 KiB double buffer

    const int tid  = threadIdx.x;
    const int lane = tid & 63;
    const int c16  = lane & 15;     // batch column within wave
    const int h    = lane >> 4;     // k-group / D-row group
    const int w    = (blockIdx.x * 256 + tid) >> 6;  // global wave id
    const int row  = w * 16 + c16;  // this lane's batch row

    // ---- first-layer B fragment from x ----
    const float4 xa = *reinterpret_cast<const float4*>(x + (size_t)row * 20 + 4 * h);
    const float4 xb = *reinterpret_cast<const float4*>(x + (size_t)row * 20 + 16);
    short8 Bf = finalize_B(cvt_pk_bf16(xa.x, xa.y), cvt_pk_bf16(xa.z, xa.w),
                           cvt_pk_bf16(xb.x, xb.y), cvt_pk_bf16(xb.z, xb.w), h);

    // ---- chunk staging: global->reg early, reg->LDS late ----
    float4 sreg[V4_PER_T];
    auto stage_load = [&](int c) {
        const float4* g = reinterpret_cast<const float4*>(wstream) + (size_t)c * CHUNK_V4;
#pragma unroll
        for (int j = 0; j < V4_PER_T; ++j) sreg[j] = g[j * 256 + tid];
    };
    auto stage_write = [&](int bufi) {
        float4* d = reinterpret_cast<float4*>(lds + bufi * CHUNK_BY);
#pragma unroll
        for (int j = 0; j < V4_PER_T; ++j) d[j * 256 + tid] = sreg[j];
    };

    const unsigned lbase = (unsigned)(uintptr_t)&lds[0];

    stage_load(0); stage_write(0); __syncthreads();

    // 4 named A-fragment buffers; buf[l & 3] holds layer l's fragments.
    short8 f0a, f0b, f1a, f1b, f2a, f2b, f3a, f3b;

    const unsigned cb0 = lbase + lane * 16;
    issue_frag(cb0,            f0a, f0b);   // layer 0
    issue_frag(cb0 + LAYER_BY, f1a, f1b);   // layer 1

    f32x2 q0, q1, q2, q3;

    const int NC = L / CL;   // 50
    for (int c = 0; c < NC; ++c) {
        if (c + 1 < NC) stage_load(c + 1);           // global prefetch (vmcnt)
        const unsigned cb = lbase + (c & 1) * CHUNK_BY + lane * 16;
#pragma unroll
        for (int ll = 0; ll < CL; ++ll) {
            // Counted wait: 4 reads outstanding (ll, ll+1); wait oldest 2.
            if (ll == CL - 1) asm volatile("s_waitcnt lgkmcnt(0)");
            else              asm volatile("s_waitcnt lgkmcnt(2)");
            __builtin_amdgcn_sched_barrier(0);       // rule #18
            if (ll + 2 < CL) {
                const unsigned a = cb + (ll + 2) * LAYER_BY;
                const int bi = (ll + 2) & 3;
                if      (bi == 0) issue_frag(a, f0a, f0b);
                else if (bi == 1) issue_frag(a, f1a, f1b);
                else if (bi == 2) issue_frag(a, f2a, f2b);
                else              issue_frag(a, f3a, f3b);
            }
            __builtin_amdgcn_sched_barrier(0);
            const int ci = ll & 3;
            if      (ci == 0) layer_step(f0a, f0b, Bf, q0, q1, q2, q3, h);
            else if (ci == 1) layer_step(f1a, f1b, Bf, q0, q1, q2, q3, h);
            else if (ci == 2) layer_step(f2a, f2b, Bf, q0, q1, q2, q3, h);
            else              layer_step(f3a, f3b, Bf, q0, q1, q2, q3, h);
        }
        if (c + 1 < NC) {
            stage_write((c + 1) & 1);                // loads long since landed
            __syncthreads();
            const unsigned nb = lbase + ((c + 1) & 1) * CHUNK_BY + lane * 16;
            issue_frag(nb,            f0a, f0b);     // next chunk layer 0
            issue_frag(nb + LAYER_BY, f1a, f1b);     // next chunk layer 1
        }
    }

    // ---- epilogue: lane (h,c16) holds neurons {4h+j} (q0,q1) and
    // {16+4h+j} (q2,q3; real only for h==0) ----
    const float4 woa = *reinterpret_cast<const float4*>(Wout + 4 * h);
    const float4 wob = *reinterpret_cast<const float4*>(Wout + 16);
    float part = q0.x * woa.x + q0.y * woa.y + q1.x * woa.z + q1.y * woa.w;
    const float m = (h == 0) ? 1.f : 0.f;
    part += m * (q2.x * wob.x + q2.y * wob.y + q3.x * wob.z + q3.y * wob.w);
    part += __shfl_xor(part, 16, 64);
    part += __shfl_xor(part, 32, 64);
    if (h == 0) out[row] = sigm(part + bout[0]);
}

extern "C" void kernel_launch(void* const* d_in, const int* in_sizes, int n_in,
                              void* d_out, int out_size, void* d_ws, size_t ws_size,
                              hipStream_t stream) {
    const float* x    = (const float*)d_in[0];
    const float* W    = (const float*)d_in[1];
    const float* b    = (const float*)d_in[2];
    const float* Wout = (const float*)d_in[3];
    const float* bout = (const float*)d_in[4];
    float* out = (float*)d_out;

    const int B = in_sizes[0] / 20;    // 16384
    const int L = in_sizes[1] / 400;   // 1000

    unsigned int* wstream = (unsigned int*)d_ws;   // L*2048 B = 2.05 MB

    prepack<<<L, 128, 0, stream>>>(W, b, wstream, L);

    const int grid = B / 64;           // 16 rows/wave, 4 waves/block
    mann_mfma<<<grid, 256, 0, stream>>>(x, wstream, Wout, bout, out, B, L);
}